// Round 5
// baseline (138.282 us; speedup 1.0000x reference)
//
#include <hip/hip_runtime.h>
#include <math.h>

#define NPAIR  2
#define KDIM   64
#define NKP    400
#define NPADR  448           /* keypoints padded to 14*32 */
#define DSTR   14            /* double-strips of 32 keypoint rows */
#define HWPIX  65536
#define MREF   70.0f         /* fixed softmax reference: logits = 100*cos <= 100 */
#define LOG2E  1.44269504f

/* ws layout (dwords):
   [0, AFRAG_DW)  : tgt A-fragments [p][d][rt][ks][hi/lo][lane][4dw], bf16 pairs
   [AFRAG_DW, ..) : partials [p][448][512 mb][2 mq] float2 {S, U_local(0..63)} */
#define AFRAG_DW (NPAIR*DSTR*2*2*2*256)   /* 57344 dwords */

using frag_ab = __attribute__((ext_vector_type(8))) short;   // 8 bf16
using f32x4   = __attribute__((ext_vector_type(4))) float;

__device__ __forceinline__ unsigned short f2bf(float f){
    unsigned u = __builtin_bit_cast(unsigned, f);
    u += 0x7fffu + ((u >> 16) & 1u);          // round-to-nearest-even
    return (unsigned short)(u >> 16);
}
__device__ __forceinline__ float bf2f(unsigned short h){
    unsigned u = ((unsigned)h) << 16;
    return __builtin_bit_cast(float, u);
}
/* butterfly sum over 16-lane row groups, pure VALU (DPP) */
__device__ __forceinline__ float red16(float v){
    v += __builtin_bit_cast(float, __builtin_amdgcn_update_dpp(0, __builtin_bit_cast(int, v), 0xB1,  0xF, 0xF, true)); // xor1
    v += __builtin_bit_cast(float, __builtin_amdgcn_update_dpp(0, __builtin_bit_cast(int, v), 0x4E,  0xF, 0xF, true)); // xor2
    v += __builtin_bit_cast(float, __builtin_amdgcn_update_dpp(0, __builtin_bit_cast(int, v), 0x141, 0xF, 0xF, true)); // half-mirror
    v += __builtin_bit_cast(float, __builtin_amdgcn_update_dpp(0, __builtin_bit_cast(int, v), 0x140, 0xF, 0xF, true)); // mirror
    return v;
}

/* normalize tgt desc, split to bf16 hi/lo, store in MFMA A-frag order.
   Coalesced: stage the [64c][32n] strip via LDS first. */
__global__ __launch_bounds__(256) void prep_kernel(
    const float* __restrict__ ksc, const float* __restrict__ kd,
    const int* __restrict__ tgt_ids, const int* __restrict__ src_ids,
    unsigned* __restrict__ wsu, float* __restrict__ out)
{
    __shared__ float xs[KDIM][33];
    __shared__ float inv_s[32];
    int d = blockIdx.x, p = blockIdx.y, t = threadIdx.x;
    int tgt = tgt_ids[p];
    int nl = t & 31, c0 = t >> 5;
    #pragma unroll
    for (int cc = 0; cc < 8; ++cc){
        int c = cc*8 + c0;
        int n = d*32 + nl;
        xs[c][nl] = (n < NKP) ? kd[(tgt*KDIM + c)*NKP + n] : 0.f;
    }
    __syncthreads();
    if (t < 32){
        float s = 0.f;
        #pragma unroll
        for (int c = 0; c < KDIM; ++c){ float v = xs[c][t]; s = fmaf(v, v, s); }
        inv_s[t] = 1.f / fmaxf(sqrtf(s), 1e-12f);
    }
    __syncthreads();
    {
        int l = t & 63, rk = t >> 6;
        int rt = rk >> 1, ks = rk & 1;
        int cl = l & 15, g = l >> 4;
        int nloc = rt*16 + cl;
        float inv = inv_s[nloc];
        int k0 = ks*32 + g*8;
        unsigned hu[4], lu[4];
        #pragma unroll
        for (int j2 = 0; j2 < 4; ++j2){
            float xa = xs[k0 + 2*j2    ][nloc] * inv;
            float xb = xs[k0 + 2*j2 + 1][nloc] * inv;
            unsigned short ha = f2bf(xa), hb = f2bf(xb);
            unsigned short la = f2bf(xa - bf2f(ha)), lb = f2bf(xb - bf2f(hb));
            hu[j2] = (unsigned)ha | ((unsigned)hb << 16);
            lu[j2] = (unsigned)la | ((unsigned)lb << 16);
        }
        unsigned base = (unsigned)((((p*DSTR + d)*2 + rt)*2 + ks)*2)*256 + l*4;
        *(uint4*)&wsu[base]       = make_uint4(hu[0], hu[1], hu[2], hu[3]);
        *(uint4*)&wsu[base + 256] = make_uint4(lu[0], lu[1], lu[2], lu[3]);
    }
    if (t < 32){
        int n = d*32 + t;
        if (n < NKP) out[NPAIR*NKP*2 + p*NKP + n] = ksc[tgt*NKP + n];
    }
    if (d == 0 && t == 0){
        out[NPAIR*NKP*3 + p]         = (float)tgt;
        out[NPAIR*NKP*3 + NPAIR + p] = (float)src_ids[p];
    }
}

/* one block per (pair, 128-pixel half-row): 34 KB LDS -> 4 blocks/CU,
   16 waves/CU. Each wave owns a 64-px quarter (mq) and 7 of 14 d-strips:
   acc[2][4] = 32 regs. Streaming staging, barrier-free MFMA main loop. */
__global__ __launch_bounds__(256, 4) void match_kernel(
    const float* __restrict__ dd, const int* __restrict__ src_ids,
    const unsigned* __restrict__ wsu, float* __restrict__ part)
{
    __shared__ unsigned lds[8192];    // hi plane [0,4096) dw, lo plane [4096,8192)
    __shared__ float ssp[256];        // per (khalf, m) sum-sq partials
    __shared__ float invn_s[128];
    int mb = blockIdx.x, p = blockIdx.y, t = threadIdx.x;
    const float* plane = dd + (size_t)src_ids[p]*KDIM*HWPIX + mb*128;

    /* staging: thread t owns (pixel m = t&127, k-half = t>>7); 32 floats:
       split RAW values to bf16 hi/lo, accumulate partial sum-sq. */
    {
        int m = t & 127, kh = t >> 7;
        unsigned sw7 = (unsigned)(m & 7) << 2;
        float ssum = 0.f;
        #pragma unroll
        for (int s2l = 0; s2l < 4; ++s2l){
            int s2 = kh*4 + s2l;
            float v[8];
            #pragma unroll
            for (int j = 0; j < 8; ++j) v[j] = plane[(size_t)(s2*8 + j)*HWPIX + m];
            unsigned hq[4], lq[4];
            #pragma unroll
            for (int q = 0; q < 4; ++q){
                float a = v[2*q], b = v[2*q + 1];
                ssum = fmaf(a, a, ssum);
                ssum = fmaf(b, b, ssum);
                unsigned short ha = f2bf(a), hb = f2bf(b);
                unsigned short la = f2bf(a - bf2f(ha)), lb = f2bf(b - bf2f(hb));
                hq[q] = (unsigned)ha | ((unsigned)hb << 16);
                lq[q] = (unsigned)la | ((unsigned)lb << 16);
            }
            unsigned dwb = (unsigned)m*32 + (((unsigned)s2 << 2) ^ sw7);
            *(uint4*)&lds[dwb]        = make_uint4(hq[0], hq[1], hq[2], hq[3]);
            *(uint4*)&lds[4096 + dwb] = make_uint4(lq[0], lq[1], lq[2], lq[3]);
        }
        ssp[t] = ssum;
    }
    __syncthreads();
    if (t < 128)
        invn_s[t] = (100.f * LOG2E) / fmaxf(sqrtf(ssp[t] + ssp[t + 128]), 1e-12f);
    __syncthreads();

    int w = t >> 6, l = t & 63;
    int cl = l & 15, g = l >> 4;
    int mq = w & 1;              // which 64-pixel quarter this wave owns
    int mtb = mq << 2;           // first 16-px tile index
    const float mref2 = MREF * LOG2E;
    float invm[4];
    #pragma unroll
    for (int mi = 0; mi < 4; ++mi) invm[mi] = invn_s[(mtb + mi)*16 + cl];

    #pragma unroll 1             /* forbid unroll: keeps one acc set live */
    for (int d = (w >> 1); d < DSTR; d += 2){
        /* all 8 A-frags for this strip up front (deep MLP) */
        uint4 AH[2][2], AL[2][2];
        #pragma unroll
        for (int rt = 0; rt < 2; ++rt)
        #pragma unroll
        for (int ks = 0; ks < 2; ++ks){
            unsigned base = (unsigned)((((p*DSTR + d)*2 + rt)*2 + ks)*2)*256 + l*4;
            AH[rt][ks] = *(const uint4*)&wsu[base];
            AL[rt][ks] = *(const uint4*)&wsu[base + 256];
        }
        f32x4 acc[2][4];
        #pragma unroll
        for (int rt = 0; rt < 2; ++rt)
            #pragma unroll
            for (int mi = 0; mi < 4; ++mi)
                acc[rt][mi] = (f32x4){0.f, 0.f, 0.f, 0.f};

        #pragma unroll
        for (int ks = 0; ks < 2; ++ks){
            frag_ab aH0 = __builtin_bit_cast(frag_ab, AH[0][ks]);
            frag_ab aL0 = __builtin_bit_cast(frag_ab, AL[0][ks]);
            frag_ab aH1 = __builtin_bit_cast(frag_ab, AH[1][ks]);
            frag_ab aL1 = __builtin_bit_cast(frag_ab, AL[1][ks]);
            #pragma unroll
            for (int mi = 0; mi < 4; ++mi){
                int mrow = (mtb + mi)*16 + cl;
                unsigned swm = (unsigned)(mrow & 7) << 2;
                unsigned dwb = (unsigned)mrow*32 + (((unsigned)(ks*4 + g) << 2) ^ swm);
                frag_ab BH = __builtin_bit_cast(frag_ab, *(const uint4*)&lds[dwb]);
                frag_ab BL = __builtin_bit_cast(frag_ab, *(const uint4*)&lds[4096 + dwb]);
                acc[0][mi] = __builtin_amdgcn_mfma_f32_16x16x32_bf16(aH0, BH, acc[0][mi], 0, 0, 0);
                acc[1][mi] = __builtin_amdgcn_mfma_f32_16x16x32_bf16(aH1, BH, acc[1][mi], 0, 0, 0);
                acc[0][mi] = __builtin_amdgcn_mfma_f32_16x16x32_bf16(aH0, BL, acc[0][mi], 0, 0, 0);
                acc[1][mi] = __builtin_amdgcn_mfma_f32_16x16x32_bf16(aH1, BL, acc[1][mi], 0, 0, 0);
                acc[0][mi] = __builtin_amdgcn_mfma_f32_16x16x32_bf16(aL0, BH, acc[0][mi], 0, 0, 0);
                acc[1][mi] = __builtin_amdgcn_mfma_f32_16x16x32_bf16(aL1, BH, acc[1][mi], 0, 0, 0);
            }
        }
        /* fixed-ref softmax partials; per-pixel norm (and log2e) applied here */
        #pragma unroll
        for (int rt = 0; rt < 2; ++rt)
        #pragma unroll
        for (int r = 0; r < 4; ++r){
            float sE = 0.f, sU = 0.f;
            #pragma unroll
            for (int mi = 0; mi < 4; ++mi){
                float e = exp2f(fmaf(acc[rt][mi][r], invm[mi], -mref2));
                sE += e;
                sU = fmaf(e, (float)(mi*16), sU);
            }
            sU = fmaf((float)cl, sE, sU);   // u_local in [0,64)
            sE = red16(sE); sU = red16(sU);
            if (cl == 0){
                int n = d*32 + rt*16 + g*4 + r;
                *(float2*)&part[(((size_t)(p*NPADR + n)*512 + mb)*2 + mq)*2] =
                    make_float2(sE, sU);
            }
        }
    }
}

/* one wave per (p,n): coalesced float4 partial reads, pure sum (fixed ref).
   Entry pair (mq0,mq1) of pixel-block mb sits in one float4. */
__global__ __launch_bounds__(256) void merge_kernel(
    const float* __restrict__ part, float* __restrict__ out)
{
    int wid = blockIdx.x*4 + (threadIdx.x >> 6);   // 0..799
    int l = threadIdx.x & 63;
    int p = wid / NKP, n = wid - p*NKP;
    const float* base = part + (size_t)(p*NPADR + n)*2048;  // 512 mb * 2 mq * 2 f
    float S = 0.f, U = 0.f, V = 0.f;
    #pragma unroll
    for (int k = 0; k < 8; ++k){
        int mbk = l + 64*k;
        float4 q = *(const float4*)&base[mbk*4];   // {S0,U0,S1,U1} of block mbk
        float u0 = (float)((mbk & 1)*128);
        float s = q.x + q.z;
        S += s;
        U += q.y + q.w + u0*q.x + (u0 + 64.f)*q.z;
        V = fmaf((float)(mbk >> 1), s, V);
    }
    #pragma unroll
    for (int off = 1; off < 64; off <<= 1){
        S += __shfl_xor(S, off);
        U += __shfl_xor(U, off);
        V += __shfl_xor(V, off);
    }
    if (l == 0){
        out[(p*NKP + n)*2 + 0] = U / S;
        out[(p*NKP + n)*2 + 1] = V / S;
    }
}

extern "C" void kernel_launch(void* const* d_in, const int* in_sizes, int n_in,
                              void* d_out, int out_size, void* d_ws, size_t ws_size,
                              hipStream_t stream)
{
    const float* ksc     = (const float*)d_in[0];  // keypoint_scores [4,1,400]
    const float* kd      = (const float*)d_in[1];  // keypoint_desc  [4,64,400]
    const float* dd      = (const float*)d_in[2];  // desc_dense     [4,64,256,256]
    const int*   tgt_ids = (const int*)d_in[3];
    const int*   src_ids = (const int*)d_in[4];
    float* out = (float*)d_out;
    unsigned* wsu = (unsigned*)d_ws;
    float* part = (float*)d_ws + AFRAG_DW;

    prep_kernel <<<dim3(DSTR, NPAIR), 256, 0, stream>>>(ksc, kd, tgt_ids, src_ids, wsu, out);
    match_kernel<<<dim3(512,  NPAIR), 256, 0, stream>>>(dd, src_ids, wsu, part);
    merge_kernel<<<200,               256, 0, stream>>>(part, out);
}

// Round 6
// 135.120 us; speedup vs baseline: 1.0234x; 1.0234x over previous
//
#include <hip/hip_runtime.h>
#include <math.h>

#define NPAIR  2
#define KDIM   64
#define NKP    400
#define NPADR  448           /* keypoints padded to 14*32 */
#define DSTR   14            /* double-strips of 32 keypoint rows */
#define HWPIX  65536
#define MREF   70.0f         /* fixed softmax reference: logits = 100*cos <= 100 */
#define LOG2E  1.44269504f

/* ws layout (dwords):
   [0, AFRAG_DW)  : tgt A-fragments [p][d][rt][ks][hi/lo][lane][4dw], bf16 pairs
   [AFRAG_DW, ..) : partials [p][448][512 mb][2 mq] float2 {S, U_local(0..63)} */
#define AFRAG_DW (NPAIR*DSTR*2*2*2*256)   /* 57344 dwords */

using frag_ab = __attribute__((ext_vector_type(8))) short;   // 8 bf16
using f32x4   = __attribute__((ext_vector_type(4))) float;

__device__ __forceinline__ unsigned short f2bf(float f){
    unsigned u = __builtin_bit_cast(unsigned, f);
    u += 0x7fffu + ((u >> 16) & 1u);          // round-to-nearest-even
    return (unsigned short)(u >> 16);
}
__device__ __forceinline__ float bf2f(unsigned short h){
    unsigned u = ((unsigned)h) << 16;
    return __builtin_bit_cast(float, u);
}
/* butterfly sum over 16-lane row groups, pure VALU (DPP) */
__device__ __forceinline__ float red16(float v){
    v += __builtin_bit_cast(float, __builtin_amdgcn_update_dpp(0, __builtin_bit_cast(int, v), 0xB1,  0xF, 0xF, true)); // xor1
    v += __builtin_bit_cast(float, __builtin_amdgcn_update_dpp(0, __builtin_bit_cast(int, v), 0x4E,  0xF, 0xF, true)); // xor2
    v += __builtin_bit_cast(float, __builtin_amdgcn_update_dpp(0, __builtin_bit_cast(int, v), 0x141, 0xF, 0xF, true)); // half-mirror
    v += __builtin_bit_cast(float, __builtin_amdgcn_update_dpp(0, __builtin_bit_cast(int, v), 0x140, 0xF, 0xF, true)); // mirror
    return v;
}

/* normalize tgt desc, split to bf16 hi/lo, store in MFMA A-frag order.
   Coalesced: stage the [64c][32n] strip via LDS first. */
__global__ __launch_bounds__(256) void prep_kernel(
    const float* __restrict__ ksc, const float* __restrict__ kd,
    const int* __restrict__ tgt_ids, const int* __restrict__ src_ids,
    unsigned* __restrict__ wsu, float* __restrict__ out)
{
    __shared__ float xs[KDIM][33];
    __shared__ float inv_s[32];
    int d = blockIdx.x, p = blockIdx.y, t = threadIdx.x;
    int tgt = tgt_ids[p];
    int nl = t & 31, c0 = t >> 5;
    #pragma unroll
    for (int cc = 0; cc < 8; ++cc){
        int c = cc*8 + c0;
        int n = d*32 + nl;
        xs[c][nl] = (n < NKP) ? kd[(tgt*KDIM + c)*NKP + n] : 0.f;
    }
    __syncthreads();
    if (t < 32){
        float s = 0.f;
        #pragma unroll
        for (int c = 0; c < KDIM; ++c){ float v = xs[c][t]; s = fmaf(v, v, s); }
        inv_s[t] = 1.f / fmaxf(sqrtf(s), 1e-12f);
    }
    __syncthreads();
    {
        int l = t & 63, rk = t >> 6;
        int rt = rk >> 1, ks = rk & 1;
        int cl = l & 15, g = l >> 4;
        int nloc = rt*16 + cl;
        float inv = inv_s[nloc];
        int k0 = ks*32 + g*8;
        unsigned hu[4], lu[4];
        #pragma unroll
        for (int j2 = 0; j2 < 4; ++j2){
            float xa = xs[k0 + 2*j2    ][nloc] * inv;
            float xb = xs[k0 + 2*j2 + 1][nloc] * inv;
            unsigned short ha = f2bf(xa), hb = f2bf(xb);
            unsigned short la = f2bf(xa - bf2f(ha)), lb = f2bf(xb - bf2f(hb));
            hu[j2] = (unsigned)ha | ((unsigned)hb << 16);
            lu[j2] = (unsigned)la | ((unsigned)lb << 16);
        }
        unsigned base = (unsigned)((((p*DSTR + d)*2 + rt)*2 + ks)*2)*256 + l*4;
        *(uint4*)&wsu[base]       = make_uint4(hu[0], hu[1], hu[2], hu[3]);
        *(uint4*)&wsu[base + 256] = make_uint4(lu[0], lu[1], lu[2], lu[3]);
    }
    if (t < 32){
        int n = d*32 + t;
        if (n < NKP) out[NPAIR*NKP*2 + p*NKP + n] = ksc[tgt*NKP + n];
    }
    if (d == 0 && t == 0){
        out[NPAIR*NKP*3 + p]         = (float)tgt;
        out[NPAIR*NKP*3 + NPAIR + p] = (float)src_ids[p];
    }
}

/* one block per (pair, 128-pixel block). Wave owns fixed (rt, mq); all 16
   B-frags (hi+lo) register-cached; 2-deep software pipeline: prefetch A(d+1),
   MFMA(d), epilogue(d-1) — independent, scheduler interleaves. */
__global__ __launch_bounds__(256, 3) void match_kernel(
    const float* __restrict__ dd, const int* __restrict__ src_ids,
    const unsigned* __restrict__ wsu, float* __restrict__ part)
{
    __shared__ unsigned lds[8192];    // hi plane [0,4096) dw, lo plane [4096,8192)
    __shared__ float ssp[256];        // per (khalf, m) sum-sq partials
    __shared__ float invn_s[128];
    int mb = blockIdx.x, p = blockIdx.y, t = threadIdx.x;
    int w = t >> 6, l = t & 63;
    int cl = l & 15, g = l >> 4;
    int mq = w & 1;              // 64-pixel quarter
    int rt = (w >> 1) & 1;       // 16-keypoint half of each 32-strip
    int mtb = mq << 2;

    /* A-frag base for this (p, rt): A(d,ks,hl) at wA + d*2048 + ks*512 + hl*256 */
    const unsigned* wA = wsu + (size_t)p*28672 + rt*1024 + (unsigned)l*4;
    uint4 Ae[4], Ao[4];
    /* prologue A-loads issue before staging (independent of LDS) */
    #pragma unroll
    for (int k = 0; k < 4; ++k) Ae[k] = *(const uint4*)(wA + 0*2048 + k*256);
    #pragma unroll
    for (int k = 0; k < 4; ++k) Ao[k] = *(const uint4*)(wA + 1*2048 + k*256);

    const float* plane = dd + (size_t)src_ids[p]*KDIM*HWPIX + mb*128;

    /* staging: thread t owns (pixel m = t&127, k-half = t>>7); 32 floats:
       split RAW values to bf16 hi/lo, accumulate partial sum-sq. */
    {
        int m = t & 127, kh = t >> 7;
        unsigned sw7 = (unsigned)(m & 7) << 2;
        float ssum = 0.f;
        #pragma unroll
        for (int s2l = 0; s2l < 4; ++s2l){
            int s2 = kh*4 + s2l;
            float v[8];
            #pragma unroll
            for (int j = 0; j < 8; ++j) v[j] = plane[(size_t)(s2*8 + j)*HWPIX + m];
            unsigned hq[4], lq[4];
            #pragma unroll
            for (int q = 0; q < 4; ++q){
                float a = v[2*q], b = v[2*q + 1];
                ssum = fmaf(a, a, ssum);
                ssum = fmaf(b, b, ssum);
                unsigned short ha = f2bf(a), hb = f2bf(b);
                unsigned short la = f2bf(a - bf2f(ha)), lb = f2bf(b - bf2f(hb));
                hq[q] = (unsigned)ha | ((unsigned)hb << 16);
                lq[q] = (unsigned)la | ((unsigned)lb << 16);
            }
            unsigned dwb = (unsigned)m*32 + (((unsigned)s2 << 2) ^ sw7);
            *(uint4*)&lds[dwb]        = make_uint4(hq[0], hq[1], hq[2], hq[3]);
            *(uint4*)&lds[4096 + dwb] = make_uint4(lq[0], lq[1], lq[2], lq[3]);
        }
        ssp[t] = ssum;
    }
    __syncthreads();
    if (t < 128)
        invn_s[t] = (100.f * LOG2E) / fmaxf(sqrtf(ssp[t] + ssp[t + 128]), 1e-12f);
    __syncthreads();

    const float mref2 = MREF * LOG2E;
    float invm[4];
    #pragma unroll
    for (int mi = 0; mi < 4; ++mi) invm[mi] = invn_s[(mtb + mi)*16 + cl];

    /* register-cache all 16 B fragments: [ks][mi][hi/lo] */
    uint4 Bf[2][4][2];
    #pragma unroll
    for (int ks = 0; ks < 2; ++ks)
    #pragma unroll
    for (int mi = 0; mi < 4; ++mi){
        int mrow = (mtb + mi)*16 + cl;
        unsigned swm = (unsigned)(mrow & 7) << 2;
        unsigned dwb = (unsigned)mrow*32 + (((unsigned)(ks*4 + g) << 2) ^ swm);
        Bf[ks][mi][0] = *(const uint4*)&lds[dwb];
        Bf[ks][mi][1] = *(const uint4*)&lds[4096 + dwb];
    }

    f32x4 acc0[4], acc1[4];
    float* pbase = part + (((size_t)(p*NPADR + rt*16 + g*4)*512 + mb)*2 + mq)*2;

    /* helpers inlined via lambdas */
    auto zacc = [&](f32x4* a){
        #pragma unroll
        for (int mi = 0; mi < 4; ++mi) a[mi] = (f32x4){0.f,0.f,0.f,0.f};
    };
    auto unit = [&](const uint4* A, f32x4* a){
        #pragma unroll
        for (int ks = 0; ks < 2; ++ks){
            frag_ab aH = __builtin_bit_cast(frag_ab, A[2*ks]);
            frag_ab aL = __builtin_bit_cast(frag_ab, A[2*ks + 1]);
            #pragma unroll
            for (int mi = 0; mi < 4; ++mi){
                frag_ab BH = __builtin_bit_cast(frag_ab, Bf[ks][mi][0]);
                frag_ab BL = __builtin_bit_cast(frag_ab, Bf[ks][mi][1]);
                a[mi] = __builtin_amdgcn_mfma_f32_16x16x32_bf16(aH, BH, a[mi], 0, 0, 0);
                a[mi] = __builtin_amdgcn_mfma_f32_16x16x32_bf16(aH, BL, a[mi], 0, 0, 0);
                a[mi] = __builtin_amdgcn_mfma_f32_16x16x32_bf16(aL, BH, a[mi], 0, 0, 0);
            }
        }
    };
    auto loadA = [&](int d, uint4* A){
        const unsigned* q = wA + (unsigned)d*2048;
        #pragma unroll
        for (int k = 0; k < 4; ++k) A[k] = *(const uint4*)(q + k*256);
    };
    auto epi = [&](const f32x4* a, int d){
        #pragma unroll
        for (int r = 0; r < 4; ++r){
            float sE = 0.f, sU = 0.f;
            #pragma unroll
            for (int mi = 0; mi < 4; ++mi){
                float e = exp2f(fmaf(a[mi][r], invm[mi], -mref2));
                sE += e;
                sU = fmaf(e, (float)(mi*16), sU);
            }
            sU = fmaf((float)cl, sE, sU);   // u_local in [0,64)
            sE = red16(sE); sU = red16(sU);
            if (cl == 0)
                *(float2*)&pbase[(size_t)(d*32 + r)*2048] = make_float2(sE, sU);
        }
    };

    /* software pipeline over d = 0..13 */
    zacc(acc0); unit(Ae, acc0);                       // d=0
    #pragma unroll 1
    for (int j = 0; j < 6; ++j){
        loadA(2*j + 2, Ae);
        zacc(acc1); unit(Ao, acc1);                   // d=2j+1
        epi(acc0, 2*j);                               // overlaps unit above
        loadA(2*j + 3, Ao);
        zacc(acc0); unit(Ae, acc0);                   // d=2j+2
        epi(acc1, 2*j + 1);
    }
    zacc(acc1); unit(Ao, acc1);                       // d=13
    epi(acc0, 12);
    epi(acc1, 13);
}

/* one wave per (p,n): coalesced float4 partial reads, pure sum (fixed ref).
   Entry pair (mq0,mq1) of pixel-block mb sits in one float4. */
__global__ __launch_bounds__(256) void merge_kernel(
    const float* __restrict__ part, float* __restrict__ out)
{
    int wid = blockIdx.x*4 + (threadIdx.x >> 6);   // 0..799
    int l = threadIdx.x & 63;
    int p = wid / NKP, n = wid - p*NKP;
    const float* base = part + (size_t)(p*NPADR + n)*2048;  // 512 mb * 2 mq * 2 f
    float S = 0.f, U = 0.f, V = 0.f;
    #pragma unroll
    for (int k = 0; k < 8; ++k){
        int mbk = l + 64*k;
        float4 q = *(const float4*)&base[mbk*4];   // {S0,U0,S1,U1} of block mbk
        float u0 = (float)((mbk & 1)*128);
        float s = q.x + q.z;
        S += s;
        U += q.y + q.w + u0*q.x + (u0 + 64.f)*q.z;
        V = fmaf((float)(mbk >> 1), s, V);
    }
    #pragma unroll
    for (int off = 1; off < 64; off <<= 1){
        S += __shfl_xor(S, off);
        U += __shfl_xor(U, off);
        V += __shfl_xor(V, off);
    }
    if (l == 0){
        out[(p*NKP + n)*2 + 0] = U / S;
        out[(p*NKP + n)*2 + 1] = V / S;
    }
}

extern "C" void kernel_launch(void* const* d_in, const int* in_sizes, int n_in,
                              void* d_out, int out_size, void* d_ws, size_t ws_size,
                              hipStream_t stream)
{
    const float* ksc     = (const float*)d_in[0];  // keypoint_scores [4,1,400]
    const float* kd      = (const float*)d_in[1];  // keypoint_desc  [4,64,400]
    const float* dd      = (const float*)d_in[2];  // desc_dense     [4,64,256,256]
    const int*   tgt_ids = (const int*)d_in[3];
    const int*   src_ids = (const int*)d_in[4];
    float* out = (float*)d_out;
    unsigned* wsu = (unsigned*)d_ws;
    float* part = (float*)d_ws + AFRAG_DW;

    prep_kernel <<<dim3(DSTR, NPAIR), 256, 0, stream>>>(ksc, kd, tgt_ids, src_ids, wsu, out);
    match_kernel<<<dim3(512,  NPAIR), 256, 0, stream>>>(dd, src_ids, wsu, part);
    merge_kernel<<<200,               256, 0, stream>>>(part, out);
}

// Round 8
// 126.553 us; speedup vs baseline: 1.0927x; 1.0677x over previous
//
#include <hip/hip_runtime.h>
#include <math.h>

#define NPAIR  2
#define KDIM   64
#define NKP    400
#define NTILE  28            /* keypoint 16-tiles (448 padded) */
#define HWPIX  65536
#define MREF   70.0f         /* fixed softmax reference: logits = 100*cos <= 100 */
#define LOG2E  1.44269504f

/* ws layout (dwords):
   [0, BFRAG_DW)  : tgt B-fragments [p][nt][ks][hi/lo][lane][4dw], bf16 pairs
   [BFRAG_DW, ..) : partials [p][nt][512 mb][16 j] float2 {S, U_local(0..127)} */
#define BFRAG_DW (NPAIR*NTILE*2*2*256)   /* 57344 dwords */

using frag_ab = __attribute__((ext_vector_type(8))) short;   // 8 bf16
using f32x4   = __attribute__((ext_vector_type(4))) float;

__device__ __forceinline__ unsigned short f2bf(float f){
    unsigned u = __builtin_bit_cast(unsigned, f);
    u += 0x7fffu + ((u >> 16) & 1u);          // round-to-nearest-even
    return (unsigned short)(u >> 16);
}
__device__ __forceinline__ float bf2f(unsigned short h){
    unsigned u = ((unsigned)h) << 16;
    return __builtin_bit_cast(float, u);
}

/* normalize tgt desc, split to bf16 hi/lo, store in MFMA B-frag order
   (n = lane&15, k = (lane>>4)*8 + j). */
__global__ __launch_bounds__(256) void prep_kernel(
    const float* __restrict__ ksc, const float* __restrict__ kd,
    const int* __restrict__ tgt_ids, const int* __restrict__ src_ids,
    unsigned* __restrict__ wsu, float* __restrict__ out)
{
    __shared__ float xs[KDIM][33];
    __shared__ float inv_s[32];
    int d = blockIdx.x, p = blockIdx.y, t = threadIdx.x;
    int tgt = tgt_ids[p];
    int nl = t & 31, c0 = t >> 5;
    #pragma unroll
    for (int cc = 0; cc < 8; ++cc){
        int c = cc*8 + c0;
        int n = d*32 + nl;
        xs[c][nl] = (n < NKP) ? kd[(tgt*KDIM + c)*NKP + n] : 0.f;
    }
    __syncthreads();
    if (t < 32){
        float s = 0.f;
        #pragma unroll
        for (int c = 0; c < KDIM; ++c){ float v = xs[c][t]; s = fmaf(v, v, s); }
        inv_s[t] = 1.f / fmaxf(sqrtf(s), 1e-12f);
    }
    __syncthreads();
    {
        int l = t & 63, rk = t >> 6;
        int rt = rk >> 1, ks = rk & 1;
        int cl = l & 15, g = l >> 4;
        int nloc = rt*16 + cl;
        float inv = inv_s[nloc];
        int k0 = ks*32 + g*8;
        unsigned hu[4], lu[4];
        #pragma unroll
        for (int j2 = 0; j2 < 4; ++j2){
            float xa = xs[k0 + 2*j2    ][nloc] * inv;
            float xb = xs[k0 + 2*j2 + 1][nloc] * inv;
            unsigned short ha = f2bf(xa), hb = f2bf(xb);
            unsigned short la = f2bf(xa - bf2f(ha)), lb = f2bf(xb - bf2f(hb));
            hu[j2] = (unsigned)ha | ((unsigned)hb << 16);
            lu[j2] = (unsigned)la | ((unsigned)lb << 16);
        }
        int nt = d*2 + rt;
        unsigned base = (unsigned)(((p*NTILE + nt)*2 + ks)*2)*256 + l*4;
        *(uint4*)&wsu[base]       = make_uint4(hu[0], hu[1], hu[2], hu[3]);
        *(uint4*)&wsu[base + 256] = make_uint4(lu[0], lu[1], lu[2], lu[3]);
    }
    if (t < 32){
        int n = d*32 + t;
        if (n < NKP) out[NPAIR*NKP*2 + p*NKP + n] = ksc[tgt*NKP + n];
    }
    if (d == 0 && t == 0){
        out[NPAIR*NKP*3 + p]         = (float)tgt;
        out[NPAIR*NKP*3 + NPAIR + p] = (float)src_ids[p];
    }
}

/* one block per (pair, 128-pixel block). Pixels = A operand (rows), keypoints
   = B operand (cols): softmax reduction over pixels runs over the register
   dim + 2 shfl. Per-wave partials stash in LDS (staging buffer is dead after
   the A-caches load); one end barrier + cross-wave sum -> compact partials. */
__global__ __launch_bounds__(256, 4) void match_kernel(
    const float* __restrict__ dd, const int* __restrict__ src_ids,
    const unsigned* __restrict__ wsu, float* __restrict__ part)
{
    __shared__ unsigned lds[8192];    // staging: hi [0,4096), lo [4096,8192); later wave-partials
    __shared__ float ssp[256];
    __shared__ float invn_s[128];
    int mb = blockIdx.x, p = blockIdx.y, t = threadIdx.x;
    int w = t >> 6, l = t & 63;
    int g = l >> 4;

    /* B prefetch for nt=0,1 issues before staging (independent) */
    const unsigned* wB = wsu + (unsigned)p*28672 + (unsigned)l*4;
    uint4 Bb0[4], Bb1[4];
    #pragma unroll
    for (int k = 0; k < 4; ++k) Bb0[k] = *(const uint4*)(wB + k*256);
    #pragma unroll
    for (int k = 0; k < 4; ++k) Bb1[k] = *(const uint4*)(wB + 1024 + k*256);

    const float* plane = dd + (size_t)src_ids[p]*KDIM*HWPIX + mb*128;

    /* staging: thread t owns (pixel m = t&127, k-half = t>>7); fast split:
       hi = round-half-up to bf16, lo = trunc(a - hi); v_perm packing. */
    {
        int m = t & 127, kh = t >> 7;
        unsigned sw = (unsigned)(m & 7);
        float ssum = 0.f;
        const float* cp = plane + m + (size_t)kh*32*HWPIX;
        #pragma unroll
        for (int s2l = 0; s2l < 4; ++s2l){
            float v[8];
            #pragma unroll
            for (int j = 0; j < 8; ++j) v[j] = cp[(size_t)(s2l*8 + j)*HWPIX];
            unsigned hq[4], lq[4];
            #pragma unroll
            for (int q = 0; q < 4; ++q){
                float a = v[2*q], b = v[2*q+1];
                ssum = fmaf(a, a, ssum);
                ssum = fmaf(b, b, ssum);
                unsigned ta = (__builtin_bit_cast(unsigned, a) + 0x8000u) & 0xFFFF0000u;
                unsigned tb = (__builtin_bit_cast(unsigned, b) + 0x8000u) & 0xFFFF0000u;
                float la = a - __builtin_bit_cast(float, ta);
                float lb = b - __builtin_bit_cast(float, tb);
                hq[q] = __builtin_amdgcn_perm(tb, ta, 0x07060302u);
                lq[q] = __builtin_amdgcn_perm(__builtin_bit_cast(unsigned, lb),
                                              __builtin_bit_cast(unsigned, la), 0x07060302u);
            }
            unsigned slot = ((unsigned)(kh*4 + s2l)) ^ sw;
            unsigned dwb = (unsigned)m*32 + slot*4;
            *(uint4*)&lds[dwb]        = make_uint4(hq[0], hq[1], hq[2], hq[3]);
            *(uint4*)&lds[4096 + dwb] = make_uint4(lq[0], lq[1], lq[2], lq[3]);
        }
        ssp[t] = ssum;
    }
    __syncthreads();
    if (t < 128)
        invn_s[t] = (100.f * LOG2E) / fmaxf(sqrtf(ssp[t] + ssp[t + 128]), 1e-12f);
    __syncthreads();

    /* A-cache: wave owns 32 pixels [w*32, w*32+32) = 2 m-tiles */
    int mloc0 = w*32;
    uint4 Ac[2][4];                 // [mt][ks*2 + hi/lo]
    #pragma unroll
    for (int mt = 0; mt < 2; ++mt){
        unsigned m = (unsigned)(mloc0 + mt*16 + (l & 15));
        unsigned sw = m & 7;
        #pragma unroll
        for (int k = 0; k < 4; ++k){
            unsigned slot = (((unsigned)(k >> 1))*4 + (unsigned)g) ^ sw;
            Ac[mt][k] = *(const uint4*)&lds[(unsigned)(k & 1)*4096 + m*32 + slot*4];
        }
    }
    __syncthreads();   /* staging LDS now dead for ALL waves -> reuse as wave-partials */

    const float mref2 = MREF * LOG2E;
    float invm8[2][4], ub_[2];
    #pragma unroll
    for (int mt = 0; mt < 2; ++mt){
        ub_[mt] = (float)(mloc0 + mt*16 + g*4);
        #pragma unroll
        for (int r = 0; r < 4; ++r)
            invm8[mt][r] = invn_s[mloc0 + mt*16 + g*4 + r];
    }

    f32x4 acc0[2], acc1[2];
    float* wp = (float*)lds;        /* wave-partials [w][nt][cl] float2 (3584 dw) */

    auto zacc = [&](f32x4* a){
        a[0] = (f32x4){0.f,0.f,0.f,0.f};
        a[1] = (f32x4){0.f,0.f,0.f,0.f};
    };
    auto unit = [&](const uint4* Bq, f32x4* a2){
        #pragma unroll
        for (int ks = 0; ks < 2; ++ks){
            frag_ab bH  = __builtin_bit_cast(frag_ab, Bq[ks*2]);
            frag_ab bL  = __builtin_bit_cast(frag_ab, Bq[ks*2 + 1]);
            frag_ab a0H = __builtin_bit_cast(frag_ab, Ac[0][ks*2]);
            frag_ab a0L = __builtin_bit_cast(frag_ab, Ac[0][ks*2 + 1]);
            frag_ab a1H = __builtin_bit_cast(frag_ab, Ac[1][ks*2]);
            frag_ab a1L = __builtin_bit_cast(frag_ab, Ac[1][ks*2 + 1]);
            a2[0] = __builtin_amdgcn_mfma_f32_16x16x32_bf16(a0H, bH, a2[0], 0, 0, 0);
            a2[1] = __builtin_amdgcn_mfma_f32_16x16x32_bf16(a1H, bH, a2[1], 0, 0, 0);
            a2[0] = __builtin_amdgcn_mfma_f32_16x16x32_bf16(a0H, bL, a2[0], 0, 0, 0);
            a2[1] = __builtin_amdgcn_mfma_f32_16x16x32_bf16(a1H, bL, a2[1], 0, 0, 0);
            a2[0] = __builtin_amdgcn_mfma_f32_16x16x32_bf16(a0L, bH, a2[0], 0, 0, 0);
            a2[1] = __builtin_amdgcn_mfma_f32_16x16x32_bf16(a1L, bH, a2[1], 0, 0, 0);
        }
    };
    auto loadB = [&](int nt, uint4* B){
        const unsigned* q = wB + (unsigned)nt*1024;
        #pragma unroll
        for (int k = 0; k < 4; ++k) B[k] = *(const uint4*)(q + k*256);
    };
    auto epi = [&](const f32x4* a2, int nt){
        float Ssum = 0.f, Usum = 0.f;
        #pragma unroll
        for (int mt = 0; mt < 2; ++mt){
            float e0 = __builtin_amdgcn_exp2f(fmaf(a2[mt][0], invm8[mt][0], -mref2));
            float e1 = __builtin_amdgcn_exp2f(fmaf(a2[mt][1], invm8[mt][1], -mref2));
            float e2 = __builtin_amdgcn_exp2f(fmaf(a2[mt][2], invm8[mt][2], -mref2));
            float e3 = __builtin_amdgcn_exp2f(fmaf(a2[mt][3], invm8[mt][3], -mref2));
            float Sm = (e0 + e1) + (e2 + e3);
            float Um = fmaf(e2, 2.f, e1);
            Um = fmaf(e3, 3.f, Um);
            Um = fmaf(ub_[mt], Sm, Um);
            Ssum += Sm; Usum += Um;
        }
        Ssum += __shfl_xor(Ssum, 16); Usum += __shfl_xor(Usum, 16);
        Ssum += __shfl_xor(Ssum, 32); Usum += __shfl_xor(Usum, 32);
        if (l < 16)
            *(float2*)&wp[((unsigned)(w*NTILE + nt)*16 + (unsigned)l)*2] =
                make_float2(Ssum, Usum);
    };

    /* pipeline over nt = 0..27 */
    zacc(acc0); unit(Bb0, acc0);                 // nt=0
    #pragma unroll 1
    for (int j = 0; j < 13; ++j){
        loadB(2*j + 2, Bb0);
        zacc(acc1); unit(Bb1, acc1);             // nt=2j+1
        epi(acc0, 2*j);
        loadB(2*j + 3, Bb1);
        zacc(acc0); unit(Bb0, acc0);             // nt=2j+2
        epi(acc1, 2*j + 1);
    }
    zacc(acc1); unit(Bb1, acc1);                 // nt=27
    epi(acc0, 26);
    epi(acc1, 27);

    /* cross-wave sum of the 4 wave-partials -> global compact partials */
    __syncthreads();
    for (int idx = t; idx < NTILE*16; idx += 256){
        int nt = idx >> 4, cl = idx & 15;
        float S = 0.f, U = 0.f;
        #pragma unroll
        for (int ww = 0; ww < 4; ++ww){
            float2 q = *(const float2*)&wp[((unsigned)(ww*NTILE + nt)*16 + (unsigned)cl)*2];
            S += q.x; U += q.y;
        }
        *(float2*)&part[(((size_t)p*NTILE + nt)*512 + mb)*32 + cl*2] =
            make_float2(S, U);
    }
}

/* one block per (p, nt<25): fully-coalesced float2 reads, LDS cross-wave sum */
__global__ __launch_bounds__(256) void merge_kernel(
    const float* __restrict__ part, float* __restrict__ out)
{
    __shared__ float red[3][4][16];
    int nt = blockIdx.x, p = blockIdx.y, t = threadIdx.x;
    int j = t & 15, mb0 = t >> 4;
    const float* base = part + ((size_t)(p*NTILE + nt)*512)*32;
    float S = 0.f, U = 0.f, V = 0.f;
    #pragma unroll 4
    for (int k = 0; k < 32; ++k){
        int mbk = mb0 + k*16;
        float2 q = *(const float2*)&base[(mbk*16 + j)*2];
        S += q.x;
        U += q.y + (float)((mbk & 1)*128)*q.x;
        V = fmaf((float)(mbk >> 1), q.x, V);
    }
    S += __shfl_xor(S, 16); U += __shfl_xor(U, 16); V += __shfl_xor(V, 16);
    S += __shfl_xor(S, 32); U += __shfl_xor(U, 32); V += __shfl_xor(V, 32);
    int w = t >> 6, l = t & 63;
    if (l < 16){ red[0][w][j] = S; red[1][w][j] = U; red[2][w][j] = V; }
    __syncthreads();
    if (t < 16){
        float Sf = red[0][0][t] + red[0][1][t] + red[0][2][t] + red[0][3][t];
        float Uf = red[1][0][t] + red[1][1][t] + red[1][2][t] + red[1][3][t];
        float Vf = red[2][0][t] + red[2][1][t] + red[2][2][t] + red[2][3][t];
        int n = nt*16 + t;
        out[(p*NKP + n)*2 + 0] = Uf / Sf;
        out[(p*NKP + n)*2 + 1] = Vf / Sf;
    }
}

extern "C" void kernel_launch(void* const* d_in, const int* in_sizes, int n_in,
                              void* d_out, int out_size, void* d_ws, size_t ws_size,
                              hipStream_t stream)
{
    const float* ksc     = (const float*)d_in[0];  // keypoint_scores [4,1,400]
    const float* kd      = (const float*)d_in[1];  // keypoint_desc  [4,64,400]
    const float* dd      = (const float*)d_in[2];  // desc_dense     [4,64,256,256]
    const int*   tgt_ids = (const int*)d_in[3];
    const int*   src_ids = (const int*)d_in[4];
    float* out = (float*)d_out;
    unsigned* wsu = (unsigned*)d_ws;
    float* part = (float*)d_ws + BFRAG_DW;

    prep_kernel <<<dim3(14, NPAIR),  256, 0, stream>>>(ksc, kd, tgt_ids, src_ids, wsu, out);
    match_kernel<<<dim3(512, NPAIR), 256, 0, stream>>>(dd, src_ids, wsu, part);
    merge_kernel<<<dim3(25, NPAIR),  256, 0, stream>>>(part, out);
}